// Round 17
// baseline (84.768 us; speedup 1.0000x reference)
//
#include <hip/hip_runtime.h>
#include <hip/hip_fp16.h>

#define DIM 512
#define BATCH 32

typedef _Float16 half8 __attribute__((ext_vector_type(8)));
typedef float floatx4 __attribute__((ext_vector_type(4)));

static __device__ __forceinline__ unsigned short f2h(float f) {
    __half h = __float2half(f);
    return *reinterpret_cast<unsigned short*>(&h);
}

// ---------------------------------------------------------------------------
// Kernel 1: Taylor of expm(M/2) (one wave per row, r1/r10-validated) + phase
// tables (block 128): pm[m] = e^{+i*kappa*m^2}, pj[j] = e^{-i*theta*j}.
// ---------------------------------------------------------------------------
__global__ __launch_bounds__(256) void taylor_tables(const float* __restrict__ bxp,
                                                     const float* __restrict__ bpp,
                                                     const float* __restrict__ th1p,
                                                     const float* __restrict__ th2p,
                                                     const float* __restrict__ kapp,
                                                     float2* __restrict__ E,
                                                     float2* __restrict__ pm,
                                                     float2* __restrict__ pj) {
    if (blockIdx.x == 128) {   // phase tables
        for (int u = threadIdx.x; u < 2 * DIM; u += 256) {
            if (u < DIM) {
                float s, c;
                sincosf(kapp[0] * (float)(u * u), &s, &c);
                pm[u] = make_float2(c, s);
            } else {
                const int j = u - DIM;
                float s, c;
                sincosf(-(th1p[0] + th2p[0]) * (float)j, &s, &c);
                pj[j] = make_float2(c, s);
            }
        }
        return;
    }

    const int wave = (blockIdx.x * blockDim.x + threadIdx.x) >> 6;
    const int lane = threadIdx.x & 63;
    if (wave >= DIM) return;
    const int i = wave;
    const float bx = bxp[0], bp = bpp[0];
    const float invs = 0.5f;   // s = 1 scaling
    const int o = lane - 31;
    const int j = i + o;
    const bool jvalid = (j >= 0 && j < DIM);

    float pre = 0.f, pim = 0.f;
    if (o == -1 && i >= 1)      { float g = sqrtf((float)i)       * invs; pre =  bx * g; pim = bp * g; }
    if (o ==  1 && i + 1 < DIM) { float g = sqrtf((float)(i + 1)) * invs; pre = -bx * g; pim = bp * g; }
    float ere = (o == 0 ? 1.f : 0.f) + pre;
    float eim = pim;

    const float gs = (jvalid && j >= 1)       ? sqrtf((float)j)       * invs : 0.f;
    const float hs = (jvalid && j + 1 < DIM)  ? sqrtf((float)(j + 1)) * invs : 0.f;
    const float csup_re = -bx * gs, csup_im = bp * gs;
    const float csub_re =  bx * hs, csub_im = bp * hs;

    for (int k = 2; k <= 30; ++k) {
        const float invk = 1.f / (float)k;
        float pmre = __shfl_up(pre, 1, 64),   pmim = __shfl_up(pim, 1, 64);
        float ppre = __shfl_down(pre, 1, 64), ppim = __shfl_down(pim, 1, 64);
        if (lane == 0)  { pmre = 0.f; pmim = 0.f; }
        if (lane == 63) { ppre = 0.f; ppim = 0.f; }
        float nre = pmre * csup_re - pmim * csup_im + ppre * csub_re - ppim * csub_im;
        float nim = pmre * csup_im + pmim * csup_re + ppre * csub_im + ppim * csub_re;
        pre = nre * invk; pim = nim * invk;
        ere += pre; eim += pim;
    }

    for (int base = 0; base < DIM; base += 64) {
        const int c = base + lane;
        const int src = c - i + 31;
        const float tre = __shfl(ere, src & 63, 64);
        const float tim = __shfl(eim, src & 63, 64);
        float vre = 0.f, vim = 0.f;
        if (src >= 0 && src < 64) { vre = tre; vim = tim; }
        E[i * DIM + c] = make_float2(vre, vim);
    }
}

// ---------------------------------------------------------------------------
// Kernel 2: single squaring fused with phase fold, 32x32 tiles (256 blocks).
//   D = E*E;  D' = pm[i] * D[i][j] * pj[j]
//   Gp[i][2j] = fp16(Re D'), Gp[i][2j+1] = fp16(-Im D')    (r10-validated)
// ---------------------------------------------------------------------------
__global__ __launch_bounds__(256) void csq_fold32(const float2* __restrict__ A,
                                                  unsigned short* __restrict__ Gp,
                                                  const float2* __restrict__ pm,
                                                  const float2* __restrict__ pj) {
    __shared__ float2 At[16][33];
    __shared__ float2 Bt[16][33];
    const int j0 = blockIdx.x * 32, i0 = blockIdx.y * 32;
    const int tid = threadIdx.x;
    const int tx = tid & 15, ty = tid >> 4;
    const int lmin = max(0, max(i0, j0) - 32);
    const int lmax = min(DIM, min(i0, j0) + 64);

    float cre[2][2] = {{0.f}}, cim[2][2] = {{0.f}};
    for (int lt = lmin; lt < lmax; lt += 16) {
        for (int idx = tid; idx < 512; idx += 256) {
            const int r = idx >> 4, c = idx & 15;
            const int l = lt + c;
            At[c][r] = (l < lmax) ? A[(i0 + r) * DIM + l]       : make_float2(0.f, 0.f);
            Bt[c][r] = (l < lmax) ? A[(size_t)l * DIM + j0 + r] : make_float2(0.f, 0.f);
        }
        __syncthreads();
#pragma unroll
        for (int ll = 0; ll < 16; ++ll) {
            float2 a0 = At[ll][ty * 2], a1 = At[ll][ty * 2 + 1];
            float2 b0 = Bt[ll][tx * 2], b1 = Bt[ll][tx * 2 + 1];
            cre[0][0] += a0.x * b0.x - a0.y * b0.y;  cim[0][0] += a0.x * b0.y + a0.y * b0.x;
            cre[0][1] += a0.x * b1.x - a0.y * b1.y;  cim[0][1] += a0.x * b1.y + a0.y * b1.x;
            cre[1][0] += a1.x * b0.x - a1.y * b0.y;  cim[1][0] += a1.x * b0.y + a1.y * b0.x;
            cre[1][1] += a1.x * b1.x - a1.y * b1.y;  cim[1][1] += a1.x * b1.y + a1.y * b1.x;
        }
        __syncthreads();
    }

#pragma unroll
    for (int q = 0; q < 2; ++q) {
        const int m = i0 + ty * 2 + q;
        const float2 km = pm[m];
#pragma unroll
        for (int r = 0; r < 2; ++r) {
            const int j = j0 + tx * 2 + r;
            const float2 tj = pj[j];
            const float r1 = cre[q][r] * tj.x - cim[q][r] * tj.y;
            const float i1 = cre[q][r] * tj.y + cim[q][r] * tj.x;
            const float r2 = r1 * km.x - i1 * km.y;
            const float i2 = r1 * km.y + i1 * km.x;
            *reinterpret_cast<ushort2*>(Gp + (size_t)m * 1024 + 2 * j) =
                make_ushort2(f2h(r2), f2h(-i2));
        }
    }
}

// ---------------------------------------------------------------------------
// Kernel 3: no-LDS direct-fragment MFMA apply. 256-thread blocks = 4
// INDEPENDENT waves (no barriers); wave w owns k-quarter k0+32w. Per-wave
// tile 64m x 32k, acc 4x2, r15 pipeline (2-chunk x lookahead, counted waits).
// Grid (4kt,8mt,32b)=1024 blocks -> 4 blocks/CU x 4 waves = 16 waves/CU.
// Band per-row +-64: j in [m0-64, m0+128), nchunk = 4 or 6 (even).
// ---------------------------------------------------------------------------
__global__ __launch_bounds__(256, 4) void apply_fused(const unsigned short* __restrict__ Gp,
                                                      const float* __restrict__ xre,
                                                      const float* __restrict__ xim,
                                                      float* __restrict__ out) {
    // XCD-bijective swizzle (1024 = 8 XCD x 128); within an XCD, 4
    // consecutive wgid share (b, m-panel) -> Gp panel + x band L2-hot.
    const int orig = blockIdx.x;
    const int wgid = (orig & 7) * 128 + (orig >> 3);
    const int b   = wgid >> 5;
    const int rem = wgid & 31;
    const int m0  = (rem >> 2) * 64;
    const int kq  = rem & 3;                  // k-panel of 128

    const int lane = threadIdx.x & 63;
    const int w    = threadIdx.x >> 6;        // independent wave id 0..3
    const int k0   = kq * 128 + w * 32;

    const int lr = lane & 15;        // k offset within 16 / A-row
    const int lq = lane >> 4;        // quarter index 0..3
    const int lk8 = lq * 8;          // Kd offset of this lane's 8 elements

    const int jmin = max(0, m0 - 64);
    const int jmax = min(DIM, m0 + 128);
    const int nchunk = (jmax - jmin) >> 5;     // 4 or 6 (even)

    const size_t xbase = ((size_t)b * DIM + jmin + lq * 4) * DIM + k0 + lr;
    const unsigned short* gp = Gp + (size_t)(m0 + lr) * 1024 + 2 * jmin + lk8;

    floatx4 acc[4][2];
#pragma unroll
    for (int ms = 0; ms < 4; ++ms)
#pragma unroll
        for (int ns = 0; ns < 2; ++ns) {
            acc[ms][ns][0] = 0.f; acc[ms][ns][1] = 0.f;
            acc[ms][ns][2] = 0.f; acc[ms][ns][3] = 0.f;
        }

    float xrA[2][2][4], xiA[2][2][4], xrB[2][2][4], xiB[2][2][4];
    half8 hb[2][2];

#define LOADX(RR, RI, CH)                                                        \
    {                                                                            \
        _Pragma("unroll")                                                        \
        for (int s = 0; s < 2; ++s)                                              \
            _Pragma("unroll")                                                    \
            for (int ns = 0; ns < 2; ++ns)                                       \
                _Pragma("unroll")                                                \
                for (int jj = 0; jj < 4; ++jj) {                                 \
                    const size_t o = xbase + (size_t)((CH) * 32 + s * 16 + jj) * DIM + ns * 16; \
                    RR[s][ns][jj] = xre[o];                                      \
                    RI[s][ns][jj] = xim[o];                                      \
                }                                                                \
    }

#define CVTX(RR, RI)                                                             \
    {                                                                            \
        _Pragma("unroll")                                                        \
        for (int s = 0; s < 2; ++s)                                              \
            _Pragma("unroll")                                                    \
            for (int ns = 0; ns < 2; ++ns) {                                     \
                union { half8 h; ushort2 u2[4]; } u;                             \
                _Pragma("unroll")                                                \
                for (int jj = 0; jj < 4; ++jj)                                   \
                    u.u2[jj] = make_ushort2(f2h(RR[s][ns][jj]), f2h(RI[s][ns][jj])); \
                hb[s][ns] = u.h;                                                 \
            }                                                                    \
    }

#define MFMA_CH(CH)                                                              \
    {                                                                            \
        __builtin_amdgcn_s_setprio(1);                                           \
        _Pragma("unroll")                                                        \
        for (int s = 0; s < 2; ++s) {                                            \
            half8 a[4];                                                          \
            _Pragma("unroll")                                                    \
            for (int ms = 0; ms < 4; ++ms)                                       \
                a[ms] = *reinterpret_cast<const half8*>(gp + (size_t)ms * 16 * 1024 + (CH) * 64 + s * 32); \
            _Pragma("unroll")                                                    \
            for (int ms = 0; ms < 4; ++ms)                                       \
                _Pragma("unroll")                                                \
                for (int ns = 0; ns < 2; ++ns)                                   \
                    acc[ms][ns] = __builtin_amdgcn_mfma_f32_16x16x32_f16(a[ms], hb[s][ns], acc[ms][ns], 0, 0, 0); \
        }                                                                        \
        __builtin_amdgcn_s_setprio(0);                                           \
    }

    // prologue: 2 chunks of x in flight before any wait
    LOADX(xrA, xiA, 0);
    LOADX(xrB, xiB, 1);

    for (int ch = 0; ch < nchunk; ch += 2) {
        CVTX(xrA, xiA);                             // waits only x(ch)
        if (ch + 2 < nchunk) LOADX(xrA, xiA, ch + 2);
        MFMA_CH(ch);                                // A-loads L2-hot
        CVTX(xrB, xiB);                             // waits only x(ch+1)
        if (ch + 3 < nchunk) LOADX(xrB, xiB, ch + 3);
        MFMA_CH(ch + 1);
    }

    // epilogue (r8-validated C/D mapping), nontemporal stores
    const int crow = lq * 4;
#pragma unroll
    for (int ms = 0; ms < 4; ++ms) {
#pragma unroll
        for (int ns = 0; ns < 2; ++ns) {
            const int kk = k0 + ns * 16 + lr;
#pragma unroll
            for (int e = 0; e < 4; ++e) {
                const int m = m0 + ms * 16 + crow + e;
                __builtin_nontemporal_store(acc[ms][ns][e],
                                            out + ((size_t)b * DIM + m) * DIM + kk);
            }
        }
    }
#undef LOADX
#undef CVTX
#undef MFMA_CH
}

// ---------------------------------------------------------------------------
extern "C" void kernel_launch(void* const* d_in, const int* in_sizes, int n_in,
                              void* d_out, int out_size, void* d_ws, size_t ws_size,
                              hipStream_t stream) {
    const float* xre = (const float*)d_in[0];
    const float* xim = (const float*)d_in[1];
    const float* th1 = (const float*)d_in[2];
    const float* th2 = (const float*)d_in[3];
    // d_in[4] = r : squeezing generator is exactly zero -> S = I, unused.
    const float* bx  = (const float*)d_in[5];
    const float* bp  = (const float*)d_in[6];
    const float* kap = (const float*)d_in[7];
    float* out = (float*)d_out;

    char* ws = (char*)d_ws;
    float2* E           = (float2*)ws;                               // 2 MB
    unsigned short* Gp  = (unsigned short*)(ws + 2u * 1024 * 1024);  // 1 MB
    float2* pm          = (float2*)(ws + 3u * 1024 * 1024);          // 4 KB
    float2* pj          = pm + DIM;                                  // 4 KB

    // E = expm(M/2) + phase tables (129 blocks: 128 taylor + 1 tables)
    hipLaunchKernelGGL(taylor_tables, dim3(129), dim3(256), 0, stream,
                       bx, bp, th1, th2, kap, E, pm, pj);
    // D = E^2 fused with phase fold -> fp16 packed Gp
    hipLaunchKernelGGL(csq_fold32, dim3(16, 16), dim3(256), 0, stream,
                       E, Gp, pm, pj);
    // out = real(K * D'' @ x[b]) — 4 independent waves per block, 16 waves/CU
    hipLaunchKernelGGL(apply_fused, dim3(1024), dim3(256), 0, stream,
                       Gp, xre, xim, out);
}

// Round 18
// 58.998 us; speedup vs baseline: 1.4368x; 1.4368x over previous
//
#include <hip/hip_runtime.h>
#include <hip/hip_fp16.h>

#define DIM 512
#define BATCH 32

typedef _Float16 half8 __attribute__((ext_vector_type(8)));
typedef float floatx4 __attribute__((ext_vector_type(4)));

static __device__ __forceinline__ unsigned short f2h(float f) {
    __half h = __float2half(f);
    return *reinterpret_cast<unsigned short*>(&h);
}

// ---------------------------------------------------------------------------
// Kernel 1: Taylor of expm(M/2) (one wave per row, r1/r10-validated) + phase
// tables (block 128): pm[m] = e^{+i*kappa*m^2}, pj[j] = e^{-i*theta*j}.
// ---------------------------------------------------------------------------
__global__ __launch_bounds__(256) void taylor_tables(const float* __restrict__ bxp,
                                                     const float* __restrict__ bpp,
                                                     const float* __restrict__ th1p,
                                                     const float* __restrict__ th2p,
                                                     const float* __restrict__ kapp,
                                                     float2* __restrict__ E,
                                                     float2* __restrict__ pm,
                                                     float2* __restrict__ pj) {
    if (blockIdx.x == 128) {   // phase tables
        for (int u = threadIdx.x; u < 2 * DIM; u += 256) {
            if (u < DIM) {
                float s, c;
                sincosf(kapp[0] * (float)(u * u), &s, &c);
                pm[u] = make_float2(c, s);
            } else {
                const int j = u - DIM;
                float s, c;
                sincosf(-(th1p[0] + th2p[0]) * (float)j, &s, &c);
                pj[j] = make_float2(c, s);
            }
        }
        return;
    }

    const int wave = (blockIdx.x * blockDim.x + threadIdx.x) >> 6;
    const int lane = threadIdx.x & 63;
    if (wave >= DIM) return;
    const int i = wave;
    const float bx = bxp[0], bp = bpp[0];
    const float invs = 0.5f;   // s = 1 scaling
    const int o = lane - 31;
    const int j = i + o;
    const bool jvalid = (j >= 0 && j < DIM);

    float pre = 0.f, pim = 0.f;
    if (o == -1 && i >= 1)      { float g = sqrtf((float)i)       * invs; pre =  bx * g; pim = bp * g; }
    if (o ==  1 && i + 1 < DIM) { float g = sqrtf((float)(i + 1)) * invs; pre = -bx * g; pim = bp * g; }
    float ere = (o == 0 ? 1.f : 0.f) + pre;
    float eim = pim;

    const float gs = (jvalid && j >= 1)       ? sqrtf((float)j)       * invs : 0.f;
    const float hs = (jvalid && j + 1 < DIM)  ? sqrtf((float)(j + 1)) * invs : 0.f;
    const float csup_re = -bx * gs, csup_im = bp * gs;
    const float csub_re =  bx * hs, csub_im = bp * hs;

    for (int k = 2; k <= 30; ++k) {
        const float invk = 1.f / (float)k;
        float pmre = __shfl_up(pre, 1, 64),   pmim = __shfl_up(pim, 1, 64);
        float ppre = __shfl_down(pre, 1, 64), ppim = __shfl_down(pim, 1, 64);
        if (lane == 0)  { pmre = 0.f; pmim = 0.f; }
        if (lane == 63) { ppre = 0.f; ppim = 0.f; }
        float nre = pmre * csup_re - pmim * csup_im + ppre * csub_re - ppim * csub_im;
        float nim = pmre * csup_im + pmim * csup_re + ppre * csub_im + ppim * csub_re;
        pre = nre * invk; pim = nim * invk;
        ere += pre; eim += pim;
    }

    for (int base = 0; base < DIM; base += 64) {
        const int c = base + lane;
        const int src = c - i + 31;
        const float tre = __shfl(ere, src & 63, 64);
        const float tim = __shfl(eim, src & 63, 64);
        float vre = 0.f, vim = 0.f;
        if (src >= 0 && src < 64) { vre = tre; vim = tim; }
        E[i * DIM + c] = make_float2(vre, vim);
    }
}

// ---------------------------------------------------------------------------
// Kernel 2: single squaring fused with phase fold, 32x32 tiles (256 blocks).
//   D = E*E;  D' = pm[i] * D[i][j] * pj[j]
//   Gp[i][2j] = fp16(Re D'), Gp[i][2j+1] = fp16(-Im D')    (r10-validated)
// ---------------------------------------------------------------------------
__global__ __launch_bounds__(256) void csq_fold32(const float2* __restrict__ A,
                                                  unsigned short* __restrict__ Gp,
                                                  const float2* __restrict__ pm,
                                                  const float2* __restrict__ pj) {
    __shared__ float2 At[16][33];
    __shared__ float2 Bt[16][33];
    const int j0 = blockIdx.x * 32, i0 = blockIdx.y * 32;
    const int tid = threadIdx.x;
    const int tx = tid & 15, ty = tid >> 4;
    const int lmin = max(0, max(i0, j0) - 32);
    const int lmax = min(DIM, min(i0, j0) + 64);

    float cre[2][2] = {{0.f}}, cim[2][2] = {{0.f}};
    for (int lt = lmin; lt < lmax; lt += 16) {
        for (int idx = tid; idx < 512; idx += 256) {
            const int r = idx >> 4, c = idx & 15;
            const int l = lt + c;
            At[c][r] = (l < lmax) ? A[(i0 + r) * DIM + l]       : make_float2(0.f, 0.f);
            Bt[c][r] = (l < lmax) ? A[(size_t)l * DIM + j0 + r] : make_float2(0.f, 0.f);
        }
        __syncthreads();
#pragma unroll
        for (int ll = 0; ll < 16; ++ll) {
            float2 a0 = At[ll][ty * 2], a1 = At[ll][ty * 2 + 1];
            float2 b0 = Bt[ll][tx * 2], b1 = Bt[ll][tx * 2 + 1];
            cre[0][0] += a0.x * b0.x - a0.y * b0.y;  cim[0][0] += a0.x * b0.y + a0.y * b0.x;
            cre[0][1] += a0.x * b1.x - a0.y * b1.y;  cim[0][1] += a0.x * b1.y + a0.y * b1.x;
            cre[1][0] += a1.x * b0.x - a1.y * b0.y;  cim[1][0] += a1.x * b0.y + a1.y * b0.x;
            cre[1][1] += a1.x * b1.x - a1.y * b1.y;  cim[1][1] += a1.x * b1.y + a1.y * b1.x;
        }
        __syncthreads();
    }

#pragma unroll
    for (int q = 0; q < 2; ++q) {
        const int m = i0 + ty * 2 + q;
        const float2 km = pm[m];
#pragma unroll
        for (int r = 0; r < 2; ++r) {
            const int j = j0 + tx * 2 + r;
            const float2 tj = pj[j];
            const float r1 = cre[q][r] * tj.x - cim[q][r] * tj.y;
            const float i1 = cre[q][r] * tj.y + cim[q][r] * tj.x;
            const float r2 = r1 * km.x - i1 * km.y;
            const float i2 = r1 * km.y + i1 * km.x;
            *reinterpret_cast<ushort2*>(Gp + (size_t)m * 1024 + 2 * j) =
                make_ushort2(f2h(r2), f2h(-i2));
        }
    }
}

// ---------------------------------------------------------------------------
// Kernel 3: fused stage+MFMA apply — r11 structure with 8 WAVES PER BLOCK.
// Block tile 128m x 128k, 512 threads = 8 waves (4 wr x 2 wc), wave tile
// 32m x 64k, acc 2x4. Same LDS layout/pipeline/traffic as r11; only the
// wave count changes -> 16 waves/CU instead of 8. Band j in [m0-64, m0+192).
// ---------------------------------------------------------------------------
#define XS_STRIDE 72
__global__ __launch_bounds__(512, 4) void apply_fused(const unsigned short* __restrict__ Gp,
                                                      const float* __restrict__ xre,
                                                      const float* __restrict__ xim,
                                                      float* __restrict__ out) {
    __shared__ unsigned short Xs[2][128 * XS_STRIDE];   // 2 x 18.4 KB

    const int k0 = blockIdx.x * 128, m0 = blockIdx.y * 128, b = blockIdx.z;
    const int tid = threadIdx.x, lane = tid & 63, w = tid >> 6;   // w: 0..7
    const int wr = w >> 1, wc = w & 1;                            // 4 x 2
    const int lr = lane & 15, lk8 = (lane >> 4) * 8;

    const int jmin = max(0, m0 - 64);
    const int jmax = min(DIM, m0 + 192);
    const int nchunk = (jmax - jmin) >> 5;             // 6 or 8 chunks of 32 j

    // staging map: 512 threads -> (local j row 0..31, 8-wide k segment 0..15)
    const int s_jl = tid & 31;
    const int s_k  = (tid >> 5) << 3;

    const unsigned short* gp = Gp + (size_t)(m0 + wr * 32 + lr) * 1024 + 2 * jmin + lk8;
    const size_t xrow0 = ((size_t)b * DIM + jmin + s_jl) * DIM + k0 + s_k;

    floatx4 acc[2][4];
#pragma unroll
    for (int ms = 0; ms < 2; ++ms)
#pragma unroll
        for (int ns = 0; ns < 4; ++ns) {
            acc[ms][ns][0] = 0.f; acc[ms][ns][1] = 0.f;
            acc[ms][ns][2] = 0.f; acc[ms][ns][3] = 0.f;
        }

    // ---- prologue: load + pack chunk 0 into buffer 0 ----
    float4 xr[2], xi[2];
#pragma unroll
    for (int t = 0; t < 2; ++t) {
        xr[t] = *reinterpret_cast<const float4*>(xre + xrow0 + 4 * t);
        xi[t] = *reinterpret_cast<const float4*>(xim + xrow0 + 4 * t);
    }
#pragma unroll
    for (int t = 0; t < 2; ++t) {
        const int kb = s_k + 4 * t;
        *reinterpret_cast<ushort2*>(&Xs[0][(kb + 0) * XS_STRIDE + 2 * s_jl]) = make_ushort2(f2h(xr[t].x), f2h(xi[t].x));
        *reinterpret_cast<ushort2*>(&Xs[0][(kb + 1) * XS_STRIDE + 2 * s_jl]) = make_ushort2(f2h(xr[t].y), f2h(xi[t].y));
        *reinterpret_cast<ushort2*>(&Xs[0][(kb + 2) * XS_STRIDE + 2 * s_jl]) = make_ushort2(f2h(xr[t].z), f2h(xi[t].z));
        *reinterpret_cast<ushort2*>(&Xs[0][(kb + 3) * XS_STRIDE + 2 * s_jl]) = make_ushort2(f2h(xr[t].w), f2h(xi[t].w));
    }
    __syncthreads();

    int cur = 0;
    for (int ch = 0; ch < nchunk; ++ch) {
        const bool has_next = (ch + 1 < nchunk);

        // ---- issue next chunk's global loads EARLY ----
        if (has_next) {
            const size_t xrow = xrow0 + (size_t)(ch + 1) * 32 * DIM;
#pragma unroll
            for (int t = 0; t < 2; ++t) {
                xr[t] = *reinterpret_cast<const float4*>(xre + xrow + 4 * t);
                xi[t] = *reinterpret_cast<const float4*>(xim + xrow + 4 * t);
            }
        }

        // ---- MFMA current chunk (A from L2-hot Gp, B from LDS) ----
        const unsigned short* bbase = &Xs[cur][(wc * 64 + lr) * XS_STRIDE + lk8];
        __builtin_amdgcn_s_setprio(1);
#pragma unroll
        for (int s = 0; s < 2; ++s) {
            half8 a[2], bb[4];
#pragma unroll
            for (int ms = 0; ms < 2; ++ms)
                a[ms] = *reinterpret_cast<const half8*>(gp + (size_t)ms * 16 * 1024 + ch * 64 + s * 32);
#pragma unroll
            for (int ns = 0; ns < 4; ++ns)
                bb[ns] = *reinterpret_cast<const half8*>(bbase + ns * 16 * XS_STRIDE + s * 32);
#pragma unroll
            for (int ms = 0; ms < 2; ++ms)
#pragma unroll
                for (int ns = 0; ns < 4; ++ns)
                    acc[ms][ns] = __builtin_amdgcn_mfma_f32_16x16x32_f16(a[ms], bb[ns], acc[ms][ns], 0, 0, 0);
        }
        __builtin_amdgcn_s_setprio(0);

        // ---- pack next chunk into the other buffer (write-late) ----
        if (has_next) {
            unsigned short* xdst = Xs[cur ^ 1];
#pragma unroll
            for (int t = 0; t < 2; ++t) {
                const int kb = s_k + 4 * t;
                *reinterpret_cast<ushort2*>(&xdst[(kb + 0) * XS_STRIDE + 2 * s_jl]) = make_ushort2(f2h(xr[t].x), f2h(xi[t].x));
                *reinterpret_cast<ushort2*>(&xdst[(kb + 1) * XS_STRIDE + 2 * s_jl]) = make_ushort2(f2h(xr[t].y), f2h(xi[t].y));
                *reinterpret_cast<ushort2*>(&xdst[(kb + 2) * XS_STRIDE + 2 * s_jl]) = make_ushort2(f2h(xr[t].z), f2h(xi[t].z));
                *reinterpret_cast<ushort2*>(&xdst[(kb + 3) * XS_STRIDE + 2 * s_jl]) = make_ushort2(f2h(xr[t].w), f2h(xi[t].w));
            }
        }
        __syncthreads();
        cur ^= 1;
    }

    // ---- epilogue (r8-validated C/D mapping), plain stores ----
    const int crow = (lane >> 4) * 4;
#pragma unroll
    for (int ms = 0; ms < 2; ++ms) {
#pragma unroll
        for (int ns = 0; ns < 4; ++ns) {
            const int kk = k0 + wc * 64 + ns * 16 + lr;
#pragma unroll
            for (int e = 0; e < 4; ++e) {
                const int m = m0 + wr * 32 + ms * 16 + crow + e;
                out[((size_t)b * DIM + m) * DIM + kk] = acc[ms][ns][e];
            }
        }
    }
}

// ---------------------------------------------------------------------------
extern "C" void kernel_launch(void* const* d_in, const int* in_sizes, int n_in,
                              void* d_out, int out_size, void* d_ws, size_t ws_size,
                              hipStream_t stream) {
    const float* xre = (const float*)d_in[0];
    const float* xim = (const float*)d_in[1];
    const float* th1 = (const float*)d_in[2];
    const float* th2 = (const float*)d_in[3];
    // d_in[4] = r : squeezing generator is exactly zero -> S = I, unused.
    const float* bx  = (const float*)d_in[5];
    const float* bp  = (const float*)d_in[6];
    const float* kap = (const float*)d_in[7];
    float* out = (float*)d_out;

    char* ws = (char*)d_ws;
    float2* E           = (float2*)ws;                               // 2 MB
    unsigned short* Gp  = (unsigned short*)(ws + 2u * 1024 * 1024);  // 1 MB
    float2* pm          = (float2*)(ws + 3u * 1024 * 1024);          // 4 KB
    float2* pj          = pm + DIM;                                  // 4 KB

    // E = expm(M/2) + phase tables (129 blocks: 128 taylor + 1 tables)
    hipLaunchKernelGGL(taylor_tables, dim3(129), dim3(256), 0, stream,
                       bx, bp, th1, th2, kap, E, pm, pj);
    // D = E^2 fused with phase fold -> fp16 packed Gp
    hipLaunchKernelGGL(csq_fold32, dim3(16, 16), dim3(256), 0, stream,
                       E, Gp, pm, pj);
    // out = real(K * D'' @ x[b]) — r11 structure, 8 waves/block, 16 waves/CU
    hipLaunchKernelGGL(apply_fused, dim3(4, 4, BATCH), dim3(512), 0, stream,
                       Gp, xre, xim, out);
}

// Round 19
// 49.966 us; speedup vs baseline: 1.6965x; 1.1808x over previous
//
#include <hip/hip_runtime.h>
#include <hip/hip_fp16.h>

#define DIM 512
#define BATCH 32

typedef _Float16 half8 __attribute__((ext_vector_type(8)));
typedef float floatx4 __attribute__((ext_vector_type(4)));

static __device__ __forceinline__ unsigned short f2h(float f) {
    __half h = __float2half(f);
    return *reinterpret_cast<unsigned short*>(&h);
}

// ---------------------------------------------------------------------------
// Kernel 1: Taylor of expm(M/2) (one wave per row, r1/r10-validated) + phase
// tables (block 128): pm[m] = e^{+i*kappa*m^2}, pj[j] = e^{-i*theta*j}.
// ---------------------------------------------------------------------------
__global__ __launch_bounds__(256) void taylor_tables(const float* __restrict__ bxp,
                                                     const float* __restrict__ bpp,
                                                     const float* __restrict__ th1p,
                                                     const float* __restrict__ th2p,
                                                     const float* __restrict__ kapp,
                                                     float2* __restrict__ E,
                                                     float2* __restrict__ pm,
                                                     float2* __restrict__ pj) {
    if (blockIdx.x == 128) {   // phase tables
        for (int u = threadIdx.x; u < 2 * DIM; u += 256) {
            if (u < DIM) {
                float s, c;
                sincosf(kapp[0] * (float)(u * u), &s, &c);
                pm[u] = make_float2(c, s);
            } else {
                const int j = u - DIM;
                float s, c;
                sincosf(-(th1p[0] + th2p[0]) * (float)j, &s, &c);
                pj[j] = make_float2(c, s);
            }
        }
        return;
    }

    const int wave = (blockIdx.x * blockDim.x + threadIdx.x) >> 6;
    const int lane = threadIdx.x & 63;
    if (wave >= DIM) return;
    const int i = wave;
    const float bx = bxp[0], bp = bpp[0];
    const float invs = 0.5f;   // s = 1 scaling
    const int o = lane - 31;
    const int j = i + o;
    const bool jvalid = (j >= 0 && j < DIM);

    float pre = 0.f, pim = 0.f;
    if (o == -1 && i >= 1)      { float g = sqrtf((float)i)       * invs; pre =  bx * g; pim = bp * g; }
    if (o ==  1 && i + 1 < DIM) { float g = sqrtf((float)(i + 1)) * invs; pre = -bx * g; pim = bp * g; }
    float ere = (o == 0 ? 1.f : 0.f) + pre;
    float eim = pim;

    const float gs = (jvalid && j >= 1)       ? sqrtf((float)j)       * invs : 0.f;
    const float hs = (jvalid && j + 1 < DIM)  ? sqrtf((float)(j + 1)) * invs : 0.f;
    const float csup_re = -bx * gs, csup_im = bp * gs;
    const float csub_re =  bx * hs, csub_im = bp * hs;

    for (int k = 2; k <= 30; ++k) {
        const float invk = 1.f / (float)k;
        float pmre = __shfl_up(pre, 1, 64),   pmim = __shfl_up(pim, 1, 64);
        float ppre = __shfl_down(pre, 1, 64), ppim = __shfl_down(pim, 1, 64);
        if (lane == 0)  { pmre = 0.f; pmim = 0.f; }
        if (lane == 63) { ppre = 0.f; ppim = 0.f; }
        float nre = pmre * csup_re - pmim * csup_im + ppre * csub_re - ppim * csub_im;
        float nim = pmre * csup_im + pmim * csup_re + ppre * csub_im + ppim * csub_re;
        pre = nre * invk; pim = nim * invk;
        ere += pre; eim += pim;
    }

    for (int base = 0; base < DIM; base += 64) {
        const int c = base + lane;
        const int src = c - i + 31;
        const float tre = __shfl(ere, src & 63, 64);
        const float tim = __shfl(eim, src & 63, 64);
        float vre = 0.f, vim = 0.f;
        if (src >= 0 && src < 64) { vre = tre; vim = tim; }
        E[i * DIM + c] = make_float2(vre, vim);
    }
}

// ---------------------------------------------------------------------------
// Kernel 2: single squaring fused with phase fold, 32x32 tiles (256 blocks).
//   D = E*E;  D' = pm[i] * D[i][j] * pj[j]
//   Gp[i][2j] = fp16(Re D'), Gp[i][2j+1] = fp16(-Im D')    (r10-validated)
// ---------------------------------------------------------------------------
__global__ __launch_bounds__(256) void csq_fold32(const float2* __restrict__ A,
                                                  unsigned short* __restrict__ Gp,
                                                  const float2* __restrict__ pm,
                                                  const float2* __restrict__ pj) {
    __shared__ float2 At[16][33];
    __shared__ float2 Bt[16][33];
    const int j0 = blockIdx.x * 32, i0 = blockIdx.y * 32;
    const int tid = threadIdx.x;
    const int tx = tid & 15, ty = tid >> 4;
    const int lmin = max(0, max(i0, j0) - 32);
    const int lmax = min(DIM, min(i0, j0) + 64);

    float cre[2][2] = {{0.f}}, cim[2][2] = {{0.f}};
    for (int lt = lmin; lt < lmax; lt += 16) {
        for (int idx = tid; idx < 512; idx += 256) {
            const int r = idx >> 4, c = idx & 15;
            const int l = lt + c;
            At[c][r] = (l < lmax) ? A[(i0 + r) * DIM + l]       : make_float2(0.f, 0.f);
            Bt[c][r] = (l < lmax) ? A[(size_t)l * DIM + j0 + r] : make_float2(0.f, 0.f);
        }
        __syncthreads();
#pragma unroll
        for (int ll = 0; ll < 16; ++ll) {
            float2 a0 = At[ll][ty * 2], a1 = At[ll][ty * 2 + 1];
            float2 b0 = Bt[ll][tx * 2], b1 = Bt[ll][tx * 2 + 1];
            cre[0][0] += a0.x * b0.x - a0.y * b0.y;  cim[0][0] += a0.x * b0.y + a0.y * b0.x;
            cre[0][1] += a0.x * b1.x - a0.y * b1.y;  cim[0][1] += a0.x * b1.y + a0.y * b1.x;
            cre[1][0] += a1.x * b0.x - a1.y * b0.y;  cim[1][0] += a1.x * b0.y + a1.y * b0.x;
            cre[1][1] += a1.x * b1.x - a1.y * b1.y;  cim[1][1] += a1.x * b1.y + a1.y * b1.x;
        }
        __syncthreads();
    }

#pragma unroll
    for (int q = 0; q < 2; ++q) {
        const int m = i0 + ty * 2 + q;
        const float2 km = pm[m];
#pragma unroll
        for (int r = 0; r < 2; ++r) {
            const int j = j0 + tx * 2 + r;
            const float2 tj = pj[j];
            const float r1 = cre[q][r] * tj.x - cim[q][r] * tj.y;
            const float i1 = cre[q][r] * tj.y + cim[q][r] * tj.x;
            const float r2 = r1 * km.x - i1 * km.y;
            const float i2 = r1 * km.y + i1 * km.x;
            *reinterpret_cast<ushort2*>(Gp + (size_t)m * 1024 + 2 * j) =
                make_ushort2(f2h(r2), f2h(-i2));
        }
    }
}

// ---------------------------------------------------------------------------
// Kernel 3: fused stage+MFMA apply — r18 structure (128x128 block tile,
// 512 thr = 8 waves 4x2, wave tile 32m x 64k) with a CONTIGUOUS staging map:
// thread t -> row (t>>3)&31, k-seg (t>>8)*64 + (t&7)*8 floats. 8 lanes cover
// a 256 B run per row (vs 32 rows x 32 B shards before) -> DRAM-friendly.
// Pack writes become 8-way bank-conflicted (accepted; LDS has slack).
// ---------------------------------------------------------------------------
#define XS_STRIDE 72
__global__ __launch_bounds__(512, 4) void apply_fused(const unsigned short* __restrict__ Gp,
                                                      const float* __restrict__ xre,
                                                      const float* __restrict__ xim,
                                                      float* __restrict__ out) {
    __shared__ unsigned short Xs[2][128 * XS_STRIDE];   // 2 x 18.4 KB

    const int k0 = blockIdx.x * 128, m0 = blockIdx.y * 128, b = blockIdx.z;
    const int tid = threadIdx.x, lane = tid & 63, w = tid >> 6;   // w: 0..7
    const int wr = w >> 1, wc = w & 1;                            // 4 x 2
    const int lr = lane & 15, lk8 = (lane >> 4) * 8;

    const int jmin = max(0, m0 - 64);
    const int jmax = min(DIM, m0 + 192);
    const int nchunk = (jmax - jmin) >> 5;             // 6 or 8 chunks of 32 j

    // CONTIGUOUS staging map: row jl, float offset s_kf (8 consecutive floats)
    const int s_jl = (tid >> 3) & 31;
    const int s_kf = (tid >> 8) * 64 + (tid & 7) * 8;

    const unsigned short* gp = Gp + (size_t)(m0 + wr * 32 + lr) * 1024 + 2 * jmin + lk8;
    const size_t xrow0 = ((size_t)b * DIM + jmin + s_jl) * DIM + k0 + s_kf;

    floatx4 acc[2][4];
#pragma unroll
    for (int ms = 0; ms < 2; ++ms)
#pragma unroll
        for (int ns = 0; ns < 4; ++ns) {
            acc[ms][ns][0] = 0.f; acc[ms][ns][1] = 0.f;
            acc[ms][ns][2] = 0.f; acc[ms][ns][3] = 0.f;
        }

    // ---- prologue: load + pack chunk 0 into buffer 0 ----
    float4 xr[2], xi[2];
#pragma unroll
    for (int t = 0; t < 2; ++t) {
        xr[t] = *reinterpret_cast<const float4*>(xre + xrow0 + 4 * t);
        xi[t] = *reinterpret_cast<const float4*>(xim + xrow0 + 4 * t);
    }
#pragma unroll
    for (int t = 0; t < 2; ++t) {
        const int kb = s_kf + 4 * t;
        *reinterpret_cast<ushort2*>(&Xs[0][(kb + 0) * XS_STRIDE + 2 * s_jl]) = make_ushort2(f2h(xr[t].x), f2h(xi[t].x));
        *reinterpret_cast<ushort2*>(&Xs[0][(kb + 1) * XS_STRIDE + 2 * s_jl]) = make_ushort2(f2h(xr[t].y), f2h(xi[t].y));
        *reinterpret_cast<ushort2*>(&Xs[0][(kb + 2) * XS_STRIDE + 2 * s_jl]) = make_ushort2(f2h(xr[t].z), f2h(xi[t].z));
        *reinterpret_cast<ushort2*>(&Xs[0][(kb + 3) * XS_STRIDE + 2 * s_jl]) = make_ushort2(f2h(xr[t].w), f2h(xi[t].w));
    }
    __syncthreads();

    int cur = 0;
    for (int ch = 0; ch < nchunk; ++ch) {
        const bool has_next = (ch + 1 < nchunk);

        // ---- issue next chunk's global loads EARLY ----
        if (has_next) {
            const size_t xrow = xrow0 + (size_t)(ch + 1) * 32 * DIM;
#pragma unroll
            for (int t = 0; t < 2; ++t) {
                xr[t] = *reinterpret_cast<const float4*>(xre + xrow + 4 * t);
                xi[t] = *reinterpret_cast<const float4*>(xim + xrow + 4 * t);
            }
        }

        // ---- MFMA current chunk (A from L2-hot Gp, B from LDS) ----
        const unsigned short* bbase = &Xs[cur][(wc * 64 + lr) * XS_STRIDE + lk8];
        __builtin_amdgcn_s_setprio(1);
#pragma unroll
        for (int s = 0; s < 2; ++s) {
            half8 a[2], bb[4];
#pragma unroll
            for (int ms = 0; ms < 2; ++ms)
                a[ms] = *reinterpret_cast<const half8*>(gp + (size_t)ms * 16 * 1024 + ch * 64 + s * 32);
#pragma unroll
            for (int ns = 0; ns < 4; ++ns)
                bb[ns] = *reinterpret_cast<const half8*>(bbase + ns * 16 * XS_STRIDE + s * 32);
#pragma unroll
            for (int ms = 0; ms < 2; ++ms)
#pragma unroll
                for (int ns = 0; ns < 4; ++ns)
                    acc[ms][ns] = __builtin_amdgcn_mfma_f32_16x16x32_f16(a[ms], bb[ns], acc[ms][ns], 0, 0, 0);
        }
        __builtin_amdgcn_s_setprio(0);

        // ---- pack next chunk into the other buffer (write-late) ----
        if (has_next) {
            unsigned short* xdst = Xs[cur ^ 1];
#pragma unroll
            for (int t = 0; t < 2; ++t) {
                const int kb = s_kf + 4 * t;
                *reinterpret_cast<ushort2*>(&xdst[(kb + 0) * XS_STRIDE + 2 * s_jl]) = make_ushort2(f2h(xr[t].x), f2h(xi[t].x));
                *reinterpret_cast<ushort2*>(&xdst[(kb + 1) * XS_STRIDE + 2 * s_jl]) = make_ushort2(f2h(xr[t].y), f2h(xi[t].y));
                *reinterpret_cast<ushort2*>(&xdst[(kb + 2) * XS_STRIDE + 2 * s_jl]) = make_ushort2(f2h(xr[t].z), f2h(xi[t].z));
                *reinterpret_cast<ushort2*>(&xdst[(kb + 3) * XS_STRIDE + 2 * s_jl]) = make_ushort2(f2h(xr[t].w), f2h(xi[t].w));
            }
        }
        __syncthreads();
        cur ^= 1;
    }

    // ---- epilogue (r8-validated C/D mapping), plain stores ----
    const int crow = (lane >> 4) * 4;
#pragma unroll
    for (int ms = 0; ms < 2; ++ms) {
#pragma unroll
        for (int ns = 0; ns < 4; ++ns) {
            const int kk = k0 + wc * 64 + ns * 16 + lr;
#pragma unroll
            for (int e = 0; e < 4; ++e) {
                const int m = m0 + wr * 32 + ms * 16 + crow + e;
                out[((size_t)b * DIM + m) * DIM + kk] = acc[ms][ns][e];
            }
        }
    }
}

// ---------------------------------------------------------------------------
extern "C" void kernel_launch(void* const* d_in, const int* in_sizes, int n_in,
                              void* d_out, int out_size, void* d_ws, size_t ws_size,
                              hipStream_t stream) {
    const float* xre = (const float*)d_in[0];
    const float* xim = (const float*)d_in[1];
    const float* th1 = (const float*)d_in[2];
    const float* th2 = (const float*)d_in[3];
    // d_in[4] = r : squeezing generator is exactly zero -> S = I, unused.
    const float* bx  = (const float*)d_in[5];
    const float* bp  = (const float*)d_in[6];
    const float* kap = (const float*)d_in[7];
    float* out = (float*)d_out;

    char* ws = (char*)d_ws;
    float2* E           = (float2*)ws;                               // 2 MB
    unsigned short* Gp  = (unsigned short*)(ws + 2u * 1024 * 1024);  // 1 MB
    float2* pm          = (float2*)(ws + 3u * 1024 * 1024);          // 4 KB
    float2* pj          = pm + DIM;                                  // 4 KB

    // E = expm(M/2) + phase tables (129 blocks: 128 taylor + 1 tables)
    hipLaunchKernelGGL(taylor_tables, dim3(129), dim3(256), 0, stream,
                       bx, bp, th1, th2, kap, E, pm, pj);
    // D = E^2 fused with phase fold -> fp16 packed Gp
    hipLaunchKernelGGL(csq_fold32, dim3(16, 16), dim3(256), 0, stream,
                       E, Gp, pm, pj);
    // out = real(K * D'' @ x[b]) — contiguous staging map, 8 waves/block
    hipLaunchKernelGGL(apply_fused, dim3(4, 4, BATCH), dim3(512), 0, stream,
                       Gp, xre, xim, out);
}